// Round 22
// baseline (589.953 us; speedup 1.0000x reference)
//
#include <hip/hip_runtime.h>
#include <math.h>
#include <stdint.h>

#define T_DATA 20000
#define E_NO   2000
#define I_NO   500
#define SUB    16
#define TNO    200
#define NBLK   313   // ceil(20000/64)
#define NAGG   1250  // agg chunks (16 t-rows each)
#define NFW    32    // filt worker blocks
#define NAW    223   // agg worker blocks (1 scan + 32 filt + 223 agg = 256)
#define FPAD   3264  // LDS pad (floats) per sE/sI -> ~95KB static -> 1 WG/CU

// ---------------------------------------------------------------------------
// K1: per-subunit kernels, hist kernel, synapse->subunit maps, tree masks.
// ---------------------------------------------------------------------------
__global__ __launch_bounds__(256) void k_prep(
    const float* __restrict__ Ce, const float* __restrict__ Ci,
    const float* __restrict__ cosb,
    const float* __restrict__ TauE, const float* __restrict__ TauI,
    const float* __restrict__ We,  const float* __restrict__ Wi,
    const float* __restrict__ De,  const float* __restrict__ Di,
    const float* __restrict__ Wsub, const float* __restrict__ Whist,
    const int* __restrict__ Cden,
    float* __restrict__ ws_ek, float* __restrict__ ws_ik,
    float* __restrict__ ws_hist, float* __restrict__ ws_ewsub,
    float* __restrict__ ws_we, float* __restrict__ ws_wi,
    int* __restrict__ ws_me, int* __restrict__ ws_mi, int* __restrict__ ws_cmask,
    float* __restrict__ out_filt) {
  int tid = threadIdx.x;
  for (int idx = tid; idx < SUB * TNO; idx += 256) {
    int s = idx / TNO;
    float tf = (float)(idx % TNO);
    float te  = fmaxf(tf - expf(De[s]), 0.f);
    float tte = te / expf(TauE[s]);
    float ekv = tte * expf(-tte) * expf(We[s]);
    float ti_ = fmaxf(tf - expf(Di[s]), 0.f);
    float tti = ti_ / expf(TauI[s]);
    float ikv = -(tti * expf(-tti) * expf(Wi[s]));
    ws_ek[idx] = ekv;
    ws_ik[idx] = ikv;
    out_filt[idx] = ekv;            // rows 0..15
    out_filt[3200 + idx] = ikv;     // rows 16..31
  }
  for (int t = tid; t < TNO; t += 256) {
    float h = 0.f;
    for (int b = 0; b < 16; ++b) h = fmaf(Whist[b], cosb[b * TNO + t], h);
    ws_hist[t] = h;
    out_filt[6400 + t] = h;         // row 32 (unflipped)
  }
  for (int e = tid; e < E_NO; e += 256) {
    int m = 0; float w = 0.f;
    for (int s = 0; s < SUB; ++s) {
      float v = Ce[s * E_NO + e];
      if (w == 0.f && v != 0.f) { m = s; w = v; }
    }
    ws_me[e] = m; ws_we[e] = w;
  }
  for (int e = tid; e < I_NO; e += 256) {
    int m = 0; float w = 0.f;
    for (int s = 0; s < SUB; ++s) {
      float v = Ci[s * I_NO + e];
      if (w == 0.f && v != 0.f) { m = s; w = v; }
    }
    ws_mi[e] = m; ws_wi[e] = w;
  }
  if (tid < SUB) {
    ws_ewsub[tid] = expf(Wsub[tid]);
    int msk = 0;
    for (int j = 0; j < SUB; ++j)
      if (Cden[tid * SUB + j] == 1) msk |= (1 << j);
    ws_cmask[tid] = msk;
  }
}

// ---------------------------------------------------------------------------
// K2 (fused, v4): producer/consumer pipeline, 256 blocks, 1 WG/CU.
//   block 0        : scan — wave0 loop BYTE-IDENTICAL to standalone R14;
//                    wave1 polls filtFlag[n+2]+fence AFTER its deep work,
//                    with an ALLDONE latch (filtCnt>=NBLK -> one final
//                    fence, then zero atomics/fences for remaining iters
//                    so wave0's L1 stays warm).
//   blocks 1..32   : filt workers, grid-stride chunks, gated on agg flags
//   blocks 33..255 : agg workers, grid-stride chunks, no deps
// ---------------------------------------------------------------------------
__global__
__attribute__((amdgpu_flat_work_group_size(256, 256), amdgpu_waves_per_eu(1, 2)))
void k_fused(
    const float4* __restrict__ Se4, const float4* __restrict__ Si4,
    const float4* __restrict__ we4, const float4* __restrict__ wi4,
    float* __restrict__ synE, float* __restrict__ synI,
    const float* __restrict__ ek_ws, const float* __restrict__ ik_ws,
    const float* __restrict__ theta, const float* __restrict__ ewsub,
    const int* __restrict__ cmask, float* __restrict__ negd,
    const float* __restrict__ hist, float* __restrict__ out_spk,
    int* __restrict__ aggFlag, int* __restrict__ filtFlag,
    int* __restrict__ filtCnt) {
  int bx = blockIdx.x;
  int tid = threadIdx.x;

  if (bx >= 33) {
    // ---------------- agg role (R17/R18 k_agg body) ----------------
    int aw = bx - 33, wid = tid >> 6, l = tid & 63;
    float4 wE0 = we4[l],       wE1 = we4[64 + l],  wE2 = we4[128 + l],
           wE3 = we4[192 + l], wE4 = we4[256 + l], wE5 = we4[320 + l],
           wE6 = we4[384 + l];
    float4 wE7 = (l < 52) ? we4[448 + l] : make_float4(0.f, 0.f, 0.f, 0.f);
    float4 wI0 = wi4[l];
    float4 wI1 = (l < 61) ? wi4[64 + l] : make_float4(0.f, 0.f, 0.f, 0.f);
    for (int c = aw; c < NAGG; c += NAW) {
      for (int r = 0; r < 4; ++r) {
        int t = (c * 4 + wid) * 4 + r;    // 16c .. 16c+15
        const float4* rowE = Se4 + (size_t)t * 500;
        const float4* rowI = Si4 + (size_t)t * 125;
        float a0 = 0.f, a1 = 0.f, a2 = 0.f, a3 = 0.f;
        float b0 = 0.f, b1 = 0.f, b2 = 0.f, b3 = 0.f;
#define ACCE(vv, wt) { a0 = fmaf((vv).x, (wt).x, a0); a1 = fmaf((vv).y, (wt).y, a1); \
                       a2 = fmaf((vv).z, (wt).z, a2); a3 = fmaf((vv).w, (wt).w, a3); }
        { float4 v = rowE[l];        ACCE(v, wE0) }
        { float4 v = rowE[64 + l];   ACCE(v, wE1) }
        { float4 v = rowE[128 + l];  ACCE(v, wE2) }
        { float4 v = rowE[192 + l];  ACCE(v, wE3) }
        { float4 v = rowE[256 + l];  ACCE(v, wE4) }
        { float4 v = rowE[320 + l];  ACCE(v, wE5) }
        { float4 v = rowE[384 + l];  ACCE(v, wE6) }
        if (l < 52) { float4 v = rowE[448 + l]; ACCE(v, wE7) }
#undef ACCE
        { float4 u = rowI[l];
          b0 = fmaf(u.x, wI0.x, b0); b1 = fmaf(u.y, wI0.y, b1);
          b2 = fmaf(u.z, wI0.z, b2); b3 = fmaf(u.w, wI0.w, b3); }
        if (l < 61) { float4 u = rowI[64 + l];
          b0 = fmaf(u.x, wI1.x, b0); b1 = fmaf(u.y, wI1.y, b1);
          b2 = fmaf(u.z, wI1.z, b2); b3 = fmaf(u.w, wI1.w, b3); }
#pragma unroll
        for (int m = 4; m <= 32; m <<= 1) {
          a0 += __shfl_xor(a0, m, 64); a1 += __shfl_xor(a1, m, 64);
          a2 += __shfl_xor(a2, m, 64); a3 += __shfl_xor(a3, m, 64);
          b0 += __shfl_xor(b0, m, 64); b1 += __shfl_xor(b1, m, 64);
          b2 += __shfl_xor(b2, m, 64); b3 += __shfl_xor(b3, m, 64);
        }
        if (l < 4) {
          ((float4*)synE)[(size_t)t * 4 + l] = make_float4(a0, a1, a2, a3);
          ((float4*)synI)[(size_t)t * 4 + l] = make_float4(b0, b1, b2, b3);
        }
      }
      __syncthreads();                 // all waves' stores issued
      __threadfence();                 // device-visible
      if (tid == 0) atomicExch(&aggFlag[c], 1);
      __syncthreads();
    }
    return;
  }

  if (bx >= 1) {
    // ---------------- filt role (R18 k_filt v2 body) ----------------
    __shared__ float sE[264 * 17 + FPAD];   // pad forces 1 WG/CU
    __shared__ float sI[264 * 17 + FPAD];
    __shared__ float ekl[TNO * 16];
    __shared__ float ikl[TNO * 16];
    __shared__ float part[64 * 17];
    int fw = bx - 1, w = tid >> 6, l = tid & 63;
    for (int idx = tid; idx < SUB * TNO; idx += 256) {
      int s = idx / TNO, j = idx % TNO;
      ekl[j * 16 + s] = ek_ws[idx];
      ikl[j * 16 + s] = ik_ws[idx];
    }
    for (int b = fw; b < NBLK; b += NFW) {
      int t0 = b * 64;
      int jmin = (t0 - 200 > 0) ? ((t0 - 200) >> 4) : 0;
      int jmax = (t0 + 63) >> 4; if (jmax > NAGG - 1) jmax = NAGG - 1;
      for (int j = jmin + tid; j <= jmax; j += 256) {
        while (atomicAdd(&aggFlag[j], 0) == 0) __builtin_amdgcn_s_sleep(16);
      }
      __syncthreads();
      __threadfence();
      for (int idx = tid; idx < 264 * 16; idx += 256) {
        int row = idx >> 4, s = idx & 15;
        int g = t0 - 200 + row;
        bool ok = (g >= 0) && (g < T_DATA);
        sE[row * 17 + s] = ok ? synE[(size_t)g * 16 + s] : 0.f;
        sI[row * 17 + s] = ok ? synI[(size_t)g * 16 + s] : 0.f;
      }
      __syncthreads();
      int sb = 4 * w;
      float acc[4];
#pragma unroll
      for (int k = 0; k < 4; ++k) acc[k] = 0.f;
      for (int j = 0; j < TNO; ++j) {
        int base = (l + 199 - j) * 17 + sb;
        int kb = j * 16 + sb;
#pragma unroll
        for (int k = 0; k < 4; ++k)
          acc[k] = fmaf(ekl[kb + k], sE[base + k], fmaf(ikl[kb + k], sI[base + k], acc[k]));
      }
#pragma unroll
      for (int k = 0; k < 4; ++k) part[l * 17 + sb + k] = acc[k];
      __syncthreads();
      if (w == 0) {
        int t = t0 + l;
        float a[16];
#pragma unroll
        for (int s = 0; s < 16; ++s) a[s] = part[l * 17 + s];
        float th[16], ew[16]; int cm[16];
#pragma unroll
        for (int s = 0; s < 16; ++s) { th[s] = theta[s]; ew[s] = ewsub[s]; cm[s] = cmask[s]; }
        float val[16];
#pragma unroll
        for (int s = 0; s < 16; ++s) val[s] = 0.f;
#pragma unroll
        for (int sidx = 15; sidx >= 1; --sidx) {
          float sum = a[sidx] + th[sidx];
#pragma unroll
          for (int j = 0; j < 16; ++j)
            if ((cm[sidx] >> j) & 1) sum += val[j] * ew[j];
          val[sidx] = tanhf(sum);
        }
        float drive = a[0] + th[0];
#pragma unroll
        for (int j = 0; j < 16; ++j)
          if ((cm[0] >> j) & 1) drive += val[j] * ew[j];
        if (t < T_DATA) negd[t] = -drive;
        __threadfence();
        if (l == 0) { atomicExch(&filtFlag[b], 1); atomicAdd(filtCnt, 1); }
      }
      __syncthreads();
    }
    return;
  }

  // ---------------- scan role: wave0 = pure R14; wave1 polls w/ latch ------
  {
    __shared__ float hpad[328];
    __shared__ unsigned long long mring[8];
    __shared__ float deepb[2][3][64];
    int wid = tid >> 6, l = tid & 63;
    for (int i = tid; i < 328; i += 256) hpad[i] = (i >= 64 && i < 264) ? hist[i - 64] : 0.f;
    if (tid < 8) mring[tid] = 0ull;
    for (int i = tid; i < 2 * 3 * 64; i += 256) (&deepb[0][0][0])[i] = 0.f;
    __syncthreads();

    // prologue gate: wave1 lane0 confirms filt blocks 0 and 1, fences.
    if (wid == 1 && l == 0) {
      while (atomicAdd(&filtFlag[0], 0) == 0) __builtin_amdgcn_s_sleep(8);
      while (atomicAdd(&filtFlag[1], 0) == 0) __builtin_amdgcn_s_sleep(8);
      __threadfence();
    }
    __syncthreads();

    float h0=0,h1=0,h2=0,h3=0,h4=0,h5=0,h6=0,h7=0,h8=0,h9=0,h10=0,h11=0,h12=0,h13=0,h14=0,h15=0,
          h16=0,h17=0,h18=0,h19=0,h20=0,h21=0,h22=0,h23=0,h24=0,h25=0,h26=0,h27=0,h28=0,h29=0,h30=0,h31=0,
          h32=0,h33=0,h34=0,h35=0,h36=0,h37=0,h38=0,h39=0,h40=0,h41=0,h42=0,h43=0,h44=0,h45=0,h46=0,h47=0,
          h48=0,h49=0,h50=0,h51=0,h52=0,h53=0,h54=0,h55=0,h56=0,h57=0,h58=0,h59=0,h60=0,h61=0,h62=0,h63=0,
          h64=0,h65=0,h66=0,h67=0,h68=0,h69=0,h70=0,h71=0,h72=0,h73=0,h74=0,h75=0,h76=0,h77=0,h78=0,h79=0,
          h80=0,h81=0,h82=0,h83=0,h84=0,h85=0,h86=0,h87=0,h88=0,h89=0,h90=0,h91=0,h92=0,h93=0,h94=0,h95=0,
          h96=0,h97=0,h98=0,h99=0,h100=0,h101=0,h102=0,h103=0,h104=0,h105=0,h106=0,h107=0,h108=0,h109=0,h110=0,h111=0,
          h112=0,h113=0,h114=0,h115=0,h116=0,h117=0,h118=0,h119=0,h120=0,h121=0,h122=0,h123=0,h124=0,h125=0,h126=0,h127=0;
    float ta0=0,ta1=0,ta2=0,ta3=0,ta4=0,ta5=0,ta6=0,ta7=0,
          ta8=0,ta9=0,ta10=0,ta11=0,ta12=0,ta13=0,ta14=0,ta15=0,
          ta16=0,ta17=0,ta18=0,ta19=0,ta20=0,ta21=0,ta22=0,ta23=0,
          ta24=0,ta25=0,ta26=0,ta27=0,ta28=0,ta29=0,ta30=0,ta31=0;
    float hd0=0,hd1=0,hd2=0,hd3=0,hd4=0,hd5=0,hd6=0,hd7=0,hd8=0,hd9=0,hd10=0,hd11=0,hd12=0,hd13=0,hd14=0,hd15=0,
          hd16=0,hd17=0,hd18=0,hd19=0,hd20=0,hd21=0,hd22=0,hd23=0,hd24=0,hd25=0,hd26=0,hd27=0,hd28=0,hd29=0,hd30=0,hd31=0,
          hd32=0,hd33=0,hd34=0,hd35=0,hd36=0,hd37=0,hd38=0,hd39=0,hd40=0,hd41=0,hd42=0,hd43=0,hd44=0,hd45=0;
    if (wid == 0) {
#define LD(j) h##j = hpad[l + j];
      LD(0)LD(1)LD(2)LD(3)LD(4)LD(5)LD(6)LD(7)LD(8)LD(9)LD(10)LD(11)LD(12)LD(13)LD(14)LD(15)
      LD(16)LD(17)LD(18)LD(19)LD(20)LD(21)LD(22)LD(23)LD(24)LD(25)LD(26)LD(27)LD(28)LD(29)LD(30)LD(31)
      LD(32)LD(33)LD(34)LD(35)LD(36)LD(37)LD(38)LD(39)LD(40)LD(41)LD(42)LD(43)LD(44)LD(45)LD(46)LD(47)
      LD(48)LD(49)LD(50)LD(51)LD(52)LD(53)LD(54)LD(55)LD(56)LD(57)LD(58)LD(59)LD(60)LD(61)LD(62)LD(63)
      LD(64)LD(65)LD(66)LD(67)LD(68)LD(69)LD(70)LD(71)LD(72)LD(73)LD(74)LD(75)LD(76)LD(77)LD(78)LD(79)
      LD(80)LD(81)LD(82)LD(83)LD(84)LD(85)LD(86)LD(87)LD(88)LD(89)LD(90)LD(91)LD(92)LD(93)LD(94)LD(95)
      LD(96)LD(97)LD(98)LD(99)LD(100)LD(101)LD(102)LD(103)LD(104)LD(105)LD(106)LD(107)LD(108)LD(109)LD(110)LD(111)
      LD(112)LD(113)LD(114)LD(115)LD(116)LD(117)LD(118)LD(119)LD(120)LD(121)LD(122)LD(123)LD(124)LD(125)LD(126)LD(127)
#undef LD
    } else {
      int dbase = (wid == 2) ? 174 : (wid == 3) ? 219 : 128;
#define LHD(j) hd##j = hpad[dbase + l + j];
      LHD(0)LHD(1)LHD(2)LHD(3)LHD(4)LHD(5)LHD(6)LHD(7)LHD(8)LHD(9)LHD(10)LHD(11)LHD(12)LHD(13)LHD(14)LHD(15)
      LHD(16)LHD(17)LHD(18)LHD(19)LHD(20)LHD(21)LHD(22)LHD(23)LHD(24)LHD(25)LHD(26)LHD(27)LHD(28)LHD(29)LHD(30)LHD(31)
      LHD(32)LHD(33)LHD(34)LHD(35)LHD(36)LHD(37)LHD(38)LHD(39)LHD(40)LHD(41)LHD(42)LHD(43)LHD(44)LHD(45)
#undef LHD
    }

    float bnd = 0.f;
    float ndv = 0.f;
    int alldone = 0;
    if (wid == 0) {
      ndv = negd[l];
      ta0 = ndv - h63;  ta1 = ndv - h61;  ta2 = ndv - h59;  ta3 = ndv - h57;
      ta4 = ndv - h55;  ta5 = ndv - h53;  ta6 = ndv - h51;  ta7 = ndv - h49;
      ta8 = ndv - h47;  ta9 = ndv - h45;  ta10 = ndv - h43; ta11 = ndv - h41;
      ta12 = ndv - h39; ta13 = ndv - h37; ta14 = ndv - h35; ta15 = ndv - h33;
      ta16 = ndv - h31; ta17 = ndv - h29; ta18 = ndv - h27; ta19 = ndv - h25;
      ta20 = ndv - h23; ta21 = ndv - h21; ta22 = ndv - h19; ta23 = ndv - h17;
      ta24 = ndv - h15; ta25 = ndv - h13; ta26 = ndv - h11; ta27 = ndv - h9;
      ta28 = ndv - h7;  ta29 = ndv - h5;  ta30 = ndv - h3;  ta31 = ndv - h1;
    }

    for (int n = 0; n < NBLK; ++n) {
      int t0 = n * 64;
      if (wid == 0) {
        // PURE R14 body — no atomics, no fences.
        int tn = t0 + 64 + l;
        float ndnext = (tn < T_DATA) ? negd[tn] : INFINITY;
        int par = n & 1;
        float X = deepb[par][0][l] + deepb[par][1][l] + deepb[par][2][l] + bnd;
        unsigned long long msk = 0ull;
        float bnd0 = 0.f, bnd1 = 0.f;
#define CH2(p, i, hvA, hvB, hbA, hbB) { \
        unsigned long long bm0, bm1; \
        asm("v_cmp_gt_f32 %0, %2, %3\n\t" \
            "v_cmp_gt_f32 %1, %2, %4" \
            : "=s"(bm0), "=s"(bm1) : "v"(X), "v"(ndv), "v"(ta##p)); \
        unsigned s0b = (unsigned)(bm0 >> (i)) & 1u; \
        unsigned long long bmx = s0b ? bm1 : bm0; \
        unsigned s1b = (unsigned)(bmx >> ((i) + 1)) & 1u; \
        float s0f = (float)s0b, s1f = (float)s1b; \
        X = fmaf(s0f, hvA, X); \
        X = fmaf(s1f, hvB, X); \
        bnd0 = fmaf(s0f, hbA, bnd0); \
        bnd1 = fmaf(s1f, hbB, bnd1); \
        ta##p = ndnext - hvA; \
        msk |= ((unsigned long long)s0b << (i)) | ((unsigned long long)s1b << ((i) + 1)); }
        CH2(0,0,h63,h62,h127,h126)   CH2(1,2,h61,h60,h125,h124)
        CH2(2,4,h59,h58,h123,h122)   CH2(3,6,h57,h56,h121,h120)
        CH2(4,8,h55,h54,h119,h118)   CH2(5,10,h53,h52,h117,h116)
        CH2(6,12,h51,h50,h115,h114)  CH2(7,14,h49,h48,h113,h112)
        CH2(8,16,h47,h46,h111,h110)  CH2(9,18,h45,h44,h109,h108)
        CH2(10,20,h43,h42,h107,h106) CH2(11,22,h41,h40,h105,h104)
        CH2(12,24,h39,h38,h103,h102) CH2(13,26,h37,h36,h101,h100)
        CH2(14,28,h35,h34,h99,h98)   CH2(15,30,h33,h32,h97,h96)
        CH2(16,32,h31,h30,h95,h94)   CH2(17,34,h29,h28,h93,h92)
        CH2(18,36,h27,h26,h91,h90)   CH2(19,38,h25,h24,h89,h88)
        CH2(20,40,h23,h22,h87,h86)   CH2(21,42,h21,h20,h85,h84)
        CH2(22,44,h19,h18,h83,h82)   CH2(23,46,h17,h16,h81,h80)
        CH2(24,48,h15,h14,h79,h78)   CH2(25,50,h13,h12,h77,h76)
        CH2(26,52,h11,h10,h75,h74)   CH2(27,54,h9,h8,h73,h72)
        CH2(28,56,h7,h6,h71,h70)     CH2(29,58,h5,h4,h69,h68)
        CH2(30,60,h3,h2,h67,h66)     CH2(31,62,h1,h0,h65,h64)
#undef CH2
        bnd = bnd0 + bnd1;
        float myspk = (float)((msk >> l) & 1ull);
        int t = t0 + l;
        if (t < T_DATA) out_spk[t] = myspk;
        if (l == 0) mring[n & 7] = msk;
        ndv = ndnext;
      } else {
        unsigned long long M1 = mring[(n + 7) & 7];
        unsigned long long M2 = mring[(n + 6) & 7];
        unsigned long long M3 = mring[(n + 5) & 7];
        M1 = ((unsigned long long)__builtin_amdgcn_readfirstlane((unsigned)(M1 >> 32)) << 32)
             | (unsigned)__builtin_amdgcn_readfirstlane((unsigned)M1);
        M2 = ((unsigned long long)__builtin_amdgcn_readfirstlane((unsigned)(M2 >> 32)) << 32)
             | (unsigned)__builtin_amdgcn_readfirstlane((unsigned)M2);
        M3 = ((unsigned long long)__builtin_amdgcn_readfirstlane((unsigned)(M3 >> 32)) << 32)
             | (unsigned)__builtin_amdgcn_readfirstlane((unsigned)M3);
        float a0 = 0.f, a1 = 0.f, a2 = 0.f, a3 = 0.f;
#define DT(j, M, b, acc) acc = fmaf((float)(((M) >> (b)) & 1ull), hd##j, acc);
        if (wid == 1) {
          DT(0,M1,63,a0)DT(1,M1,62,a1)DT(2,M1,61,a2)DT(3,M1,60,a3)
          DT(4,M1,59,a0)DT(5,M1,58,a1)DT(6,M1,57,a2)DT(7,M1,56,a3)
          DT(8,M1,55,a0)DT(9,M1,54,a1)DT(10,M1,53,a2)DT(11,M1,52,a3)
          DT(12,M1,51,a0)DT(13,M1,50,a1)DT(14,M1,49,a2)DT(15,M1,48,a3)
          DT(16,M1,47,a0)DT(17,M1,46,a1)DT(18,M1,45,a2)DT(19,M1,44,a3)
          DT(20,M1,43,a0)DT(21,M1,42,a1)DT(22,M1,41,a2)DT(23,M1,40,a3)
          DT(24,M1,39,a0)DT(25,M1,38,a1)DT(26,M1,37,a2)DT(27,M1,36,a3)
          DT(28,M1,35,a0)DT(29,M1,34,a1)DT(30,M1,33,a2)DT(31,M1,32,a3)
          DT(32,M1,31,a0)DT(33,M1,30,a1)DT(34,M1,29,a2)DT(35,M1,28,a3)
          DT(36,M1,27,a0)DT(37,M1,26,a1)DT(38,M1,25,a2)DT(39,M1,24,a3)
          DT(40,M1,23,a0)DT(41,M1,22,a1)DT(42,M1,21,a2)DT(43,M1,20,a3)
          DT(44,M1,19,a0)DT(45,M1,18,a1)
        } else if (wid == 2) {
          DT(0,M1,17,a0)DT(1,M1,16,a1)DT(2,M1,15,a2)DT(3,M1,14,a3)
          DT(4,M1,13,a0)DT(5,M1,12,a1)DT(6,M1,11,a2)DT(7,M1,10,a3)
          DT(8,M1,9,a0)DT(9,M1,8,a1)DT(10,M1,7,a2)DT(11,M1,6,a3)
          DT(12,M1,5,a0)DT(13,M1,4,a1)DT(14,M1,3,a2)DT(15,M1,2,a3)
          DT(16,M1,1,a0)DT(17,M1,0,a1)
          DT(18,M2,63,a2)DT(19,M2,62,a3)
          DT(20,M2,61,a0)DT(21,M2,60,a1)DT(22,M2,59,a2)DT(23,M2,58,a3)
          DT(24,M2,57,a0)DT(25,M2,56,a1)DT(26,M2,55,a2)DT(27,M2,54,a3)
          DT(28,M2,53,a0)DT(29,M2,52,a1)DT(30,M2,51,a2)DT(31,M2,50,a3)
          DT(32,M2,49,a0)DT(33,M2,48,a1)DT(34,M2,47,a2)DT(35,M2,46,a3)
          DT(36,M2,45,a0)DT(37,M2,44,a1)DT(38,M2,43,a2)DT(39,M2,42,a3)
          DT(40,M2,41,a0)DT(41,M2,40,a1)DT(42,M2,39,a2)DT(43,M2,38,a3)
          DT(44,M2,37,a0)
        } else {
          DT(0,M2,36,a0)DT(1,M2,35,a1)DT(2,M2,34,a2)DT(3,M2,33,a3)
          DT(4,M2,32,a0)DT(5,M2,31,a1)DT(6,M2,30,a2)DT(7,M2,29,a3)
          DT(8,M2,28,a0)DT(9,M2,27,a1)DT(10,M2,26,a2)DT(11,M2,25,a3)
          DT(12,M2,24,a0)DT(13,M2,23,a1)DT(14,M2,22,a2)DT(15,M2,21,a3)
          DT(16,M2,20,a0)DT(17,M2,19,a1)DT(18,M2,18,a2)DT(19,M2,17,a3)
          DT(20,M2,16,a0)DT(21,M2,15,a1)DT(22,M2,14,a2)DT(23,M2,13,a3)
          DT(24,M2,12,a0)DT(25,M2,11,a1)DT(26,M2,10,a2)DT(27,M2,9,a3)
          DT(28,M2,8,a0)DT(29,M2,7,a1)DT(30,M2,6,a2)DT(31,M2,5,a3)
          DT(32,M2,4,a0)DT(33,M2,3,a1)DT(34,M2,2,a2)DT(35,M2,1,a3)
          DT(36,M2,0,a0)
          DT(37,M3,63,a1)DT(38,M3,62,a2)DT(39,M3,61,a3)
          DT(40,M3,60,a0)DT(41,M3,59,a1)DT(42,M3,58,a2)DT(43,M3,57,a3)
          DT(44,M3,56,a0)
        }
#undef DT
        deepb[(n + 1) & 1][wid - 1][l] = (a0 + a1) + (a2 + a3);
        // wave1 lane0: confirm the flag wave0 needs NEXT iteration, with
        // ALLDONE latch — after filtCnt>=NBLK, zero atomics and fences.
        if (wid == 1 && l == 0 && !alldone) {
          if (atomicAdd(filtCnt, 0) >= NBLK) {
            __threadfence();
            alldone = 1;
          } else {
            int nb = n + 2; if (nb > NBLK - 1) nb = NBLK - 1;
            while (atomicAdd(&filtFlag[nb], 0) == 0) __builtin_amdgcn_s_sleep(8);
            __threadfence();
          }
        }
      }
      __syncthreads();
    }
  }
}

// ---------------------------------------------------------------------------
extern "C" void kernel_launch(void* const* d_in, const int* in_sizes, int n_in,
                              void* d_out, int out_size, void* d_ws, size_t ws_size,
                              hipStream_t stream) {
  const float* S_e      = (const float*)d_in[0];
  const float* S_i      = (const float*)d_in[1];
  const int*   C_den    = (const int*)d_in[2];
  const float* C_syn_e  = (const float*)d_in[3];
  const float* C_syn_i  = (const float*)d_in[4];
  const float* cos_b    = (const float*)d_in[5];
  const float* Tau_e    = (const float*)d_in[6];
  const float* Tau_i    = (const float*)d_in[7];
  const float* W_e      = (const float*)d_in[8];
  const float* W_i      = (const float*)d_in[9];
  const float* D_e      = (const float*)d_in[10];
  const float* D_i      = (const float*)d_in[11];
  const float* W_sub    = (const float*)d_in[12];
  const float* W_hist   = (const float*)d_in[13];
  const float* Theta    = (const float*)d_in[14];
  float* out = (float*)d_out;

  float* wsf      = (float*)d_ws;
  float* ws_ek    = wsf;
  float* ws_ik    = wsf + 3200;
  float* ws_hist  = wsf + 6400;
  float* ws_ewsub = wsf + 6600;
  float* ws_we    = wsf + 6616;
  float* ws_wi    = wsf + 8616;
  float* synE     = wsf + 16384;
  float* synI     = wsf + 336384;
  float* negd     = wsf + 656384;
  int*   ws_me    = (int*)(wsf + 676384);
  int*   ws_mi    = (int*)(wsf + 678384);
  int*   ws_cmask = (int*)(wsf + 678884);
  int*   aggFlag  = (int*)(wsf + 680000);
  int*   filtFlag = aggFlag + 1280;
  int*   filtCnt  = filtFlag + 320;

  // zero the pipeline flags every call (deterministic; ws not re-poisoned)
  hipMemsetAsync(aggFlag, 0, (1280 + 320 + 16) * sizeof(int), stream);

  k_prep<<<dim3(1), dim3(256), 0, stream>>>(
      C_syn_e, C_syn_i, cos_b, Tau_e, Tau_i, W_e, W_i, D_e, D_i, W_sub, W_hist,
      C_den, ws_ek, ws_ik, ws_hist, ws_ewsub, ws_we, ws_wi, ws_me, ws_mi,
      ws_cmask, out + T_DATA);

  k_fused<<<dim3(256), dim3(256), 0, stream>>>(
      (const float4*)S_e, (const float4*)S_i,
      (const float4*)ws_we, (const float4*)ws_wi, synE, synI,
      ws_ek, ws_ik, Theta, ws_ewsub, ws_cmask, negd,
      ws_hist, out, aggFlag, filtFlag, filtCnt);
}

// Round 23
// 571.572 us; speedup vs baseline: 1.0322x; 1.0322x over previous
//
#include <hip/hip_runtime.h>
#include <math.h>
#include <stdint.h>

#define T_DATA 20000
#define E_NO   2000
#define I_NO   500
#define SUB    16
#define TNO    200
#define NBLK   313   // ceil(20000/64)
#define NAGG   1250  // agg chunks (16 t-rows each)
#define NFW    32    // filt worker blocks
#define NAW    223   // agg worker blocks (1 scan + 32 filt + 223 agg = 256)
#define FPAD   3264  // LDS pad (floats) per sE/sI -> ~95KB static -> 1 WG/CU

// ---------------------------------------------------------------------------
// K1: per-subunit kernels, hist kernel, synapse->subunit maps, tree masks.
// ---------------------------------------------------------------------------
__global__ __launch_bounds__(256) void k_prep(
    const float* __restrict__ Ce, const float* __restrict__ Ci,
    const float* __restrict__ cosb,
    const float* __restrict__ TauE, const float* __restrict__ TauI,
    const float* __restrict__ We,  const float* __restrict__ Wi,
    const float* __restrict__ De,  const float* __restrict__ Di,
    const float* __restrict__ Wsub, const float* __restrict__ Whist,
    const int* __restrict__ Cden,
    float* __restrict__ ws_ek, float* __restrict__ ws_ik,
    float* __restrict__ ws_hist, float* __restrict__ ws_ewsub,
    float* __restrict__ ws_we, float* __restrict__ ws_wi,
    int* __restrict__ ws_me, int* __restrict__ ws_mi, int* __restrict__ ws_cmask,
    float* __restrict__ out_filt) {
  int tid = threadIdx.x;
  for (int idx = tid; idx < SUB * TNO; idx += 256) {
    int s = idx / TNO;
    float tf = (float)(idx % TNO);
    float te  = fmaxf(tf - expf(De[s]), 0.f);
    float tte = te / expf(TauE[s]);
    float ekv = tte * expf(-tte) * expf(We[s]);
    float ti_ = fmaxf(tf - expf(Di[s]), 0.f);
    float tti = ti_ / expf(TauI[s]);
    float ikv = -(tti * expf(-tti) * expf(Wi[s]));
    ws_ek[idx] = ekv;
    ws_ik[idx] = ikv;
    out_filt[idx] = ekv;            // rows 0..15
    out_filt[3200 + idx] = ikv;     // rows 16..31
  }
  for (int t = tid; t < TNO; t += 256) {
    float h = 0.f;
    for (int b = 0; b < 16; ++b) h = fmaf(Whist[b], cosb[b * TNO + t], h);
    ws_hist[t] = h;
    out_filt[6400 + t] = h;         // row 32 (unflipped)
  }
  for (int e = tid; e < E_NO; e += 256) {
    int m = 0; float w = 0.f;
    for (int s = 0; s < SUB; ++s) {
      float v = Ce[s * E_NO + e];
      if (w == 0.f && v != 0.f) { m = s; w = v; }
    }
    ws_me[e] = m; ws_we[e] = w;
  }
  for (int e = tid; e < I_NO; e += 256) {
    int m = 0; float w = 0.f;
    for (int s = 0; s < SUB; ++s) {
      float v = Ci[s * I_NO + e];
      if (w == 0.f && v != 0.f) { m = s; w = v; }
    }
    ws_mi[e] = m; ws_wi[e] = w;
  }
  if (tid < SUB) {
    ws_ewsub[tid] = expf(Wsub[tid]);
    int msk = 0;
    for (int j = 0; j < SUB; ++j)
      if (Cden[tid * SUB + j] == 1) msk |= (1 << j);
    ws_cmask[tid] = msk;
  }
}

// ---------------------------------------------------------------------------
// K2 (fused, v3 — R21 exact): producer/consumer pipeline, 256 blocks, 1 WG/CU.
//   block 0        : scan — wave0 loop BYTE-IDENTICAL to standalone R14
//                    (no atomics/fences); wave1 polls filtFlag[n+2]+fence
//                    AFTER its deep-feedback work, handed over by the
//                    existing end-of-iteration barrier.
//   blocks 1..32   : filt workers, grid-stride chunks, gated on agg flags
//   blocks 33..255 : agg workers, grid-stride chunks, no deps
// ---------------------------------------------------------------------------
__global__
__attribute__((amdgpu_flat_work_group_size(256, 256), amdgpu_waves_per_eu(1, 2)))
void k_fused(
    const float4* __restrict__ Se4, const float4* __restrict__ Si4,
    const float4* __restrict__ we4, const float4* __restrict__ wi4,
    float* __restrict__ synE, float* __restrict__ synI,
    const float* __restrict__ ek_ws, const float* __restrict__ ik_ws,
    const float* __restrict__ theta, const float* __restrict__ ewsub,
    const int* __restrict__ cmask, float* __restrict__ negd,
    const float* __restrict__ hist, float* __restrict__ out_spk,
    int* __restrict__ aggFlag, int* __restrict__ filtFlag,
    int* __restrict__ filtCnt) {
  int bx = blockIdx.x;
  int tid = threadIdx.x;

  if (bx >= 33) {
    // ---------------- agg role (R17/R18 k_agg body) ----------------
    int aw = bx - 33, wid = tid >> 6, l = tid & 63;
    float4 wE0 = we4[l],       wE1 = we4[64 + l],  wE2 = we4[128 + l],
           wE3 = we4[192 + l], wE4 = we4[256 + l], wE5 = we4[320 + l],
           wE6 = we4[384 + l];
    float4 wE7 = (l < 52) ? we4[448 + l] : make_float4(0.f, 0.f, 0.f, 0.f);
    float4 wI0 = wi4[l];
    float4 wI1 = (l < 61) ? wi4[64 + l] : make_float4(0.f, 0.f, 0.f, 0.f);
    for (int c = aw; c < NAGG; c += NAW) {
      for (int r = 0; r < 4; ++r) {
        int t = (c * 4 + wid) * 4 + r;    // 16c .. 16c+15
        const float4* rowE = Se4 + (size_t)t * 500;
        const float4* rowI = Si4 + (size_t)t * 125;
        float a0 = 0.f, a1 = 0.f, a2 = 0.f, a3 = 0.f;
        float b0 = 0.f, b1 = 0.f, b2 = 0.f, b3 = 0.f;
#define ACCE(vv, wt) { a0 = fmaf((vv).x, (wt).x, a0); a1 = fmaf((vv).y, (wt).y, a1); \
                       a2 = fmaf((vv).z, (wt).z, a2); a3 = fmaf((vv).w, (wt).w, a3); }
        { float4 v = rowE[l];        ACCE(v, wE0) }
        { float4 v = rowE[64 + l];   ACCE(v, wE1) }
        { float4 v = rowE[128 + l];  ACCE(v, wE2) }
        { float4 v = rowE[192 + l];  ACCE(v, wE3) }
        { float4 v = rowE[256 + l];  ACCE(v, wE4) }
        { float4 v = rowE[320 + l];  ACCE(v, wE5) }
        { float4 v = rowE[384 + l];  ACCE(v, wE6) }
        if (l < 52) { float4 v = rowE[448 + l]; ACCE(v, wE7) }
#undef ACCE
        { float4 u = rowI[l];
          b0 = fmaf(u.x, wI0.x, b0); b1 = fmaf(u.y, wI0.y, b1);
          b2 = fmaf(u.z, wI0.z, b2); b3 = fmaf(u.w, wI0.w, b3); }
        if (l < 61) { float4 u = rowI[64 + l];
          b0 = fmaf(u.x, wI1.x, b0); b1 = fmaf(u.y, wI1.y, b1);
          b2 = fmaf(u.z, wI1.z, b2); b3 = fmaf(u.w, wI1.w, b3); }
#pragma unroll
        for (int m = 4; m <= 32; m <<= 1) {
          a0 += __shfl_xor(a0, m, 64); a1 += __shfl_xor(a1, m, 64);
          a2 += __shfl_xor(a2, m, 64); a3 += __shfl_xor(a3, m, 64);
          b0 += __shfl_xor(b0, m, 64); b1 += __shfl_xor(b1, m, 64);
          b2 += __shfl_xor(b2, m, 64); b3 += __shfl_xor(b3, m, 64);
        }
        if (l < 4) {
          ((float4*)synE)[(size_t)t * 4 + l] = make_float4(a0, a1, a2, a3);
          ((float4*)synI)[(size_t)t * 4 + l] = make_float4(b0, b1, b2, b3);
        }
      }
      __syncthreads();                 // all waves' stores issued
      __threadfence();                 // device-visible
      if (tid == 0) atomicExch(&aggFlag[c], 1);
      __syncthreads();
    }
    return;
  }

  if (bx >= 1) {
    // ---------------- filt role (R18 k_filt v2 body) ----------------
    __shared__ float sE[264 * 17 + FPAD];   // pad forces 1 WG/CU
    __shared__ float sI[264 * 17 + FPAD];
    __shared__ float ekl[TNO * 16];
    __shared__ float ikl[TNO * 16];
    __shared__ float part[64 * 17];
    int fw = bx - 1, w = tid >> 6, l = tid & 63;
    for (int idx = tid; idx < SUB * TNO; idx += 256) {
      int s = idx / TNO, j = idx % TNO;
      ekl[j * 16 + s] = ek_ws[idx];
      ikl[j * 16 + s] = ik_ws[idx];
    }
    for (int b = fw; b < NBLK; b += NFW) {
      int t0 = b * 64;
      int jmin = (t0 - 200 > 0) ? ((t0 - 200) >> 4) : 0;
      int jmax = (t0 + 63) >> 4; if (jmax > NAGG - 1) jmax = NAGG - 1;
      for (int j = jmin + tid; j <= jmax; j += 256) {
        while (atomicAdd(&aggFlag[j], 0) == 0) __builtin_amdgcn_s_sleep(16);
      }
      __syncthreads();
      __threadfence();
      for (int idx = tid; idx < 264 * 16; idx += 256) {
        int row = idx >> 4, s = idx & 15;
        int g = t0 - 200 + row;
        bool ok = (g >= 0) && (g < T_DATA);
        sE[row * 17 + s] = ok ? synE[(size_t)g * 16 + s] : 0.f;
        sI[row * 17 + s] = ok ? synI[(size_t)g * 16 + s] : 0.f;
      }
      __syncthreads();
      int sb = 4 * w;
      float acc[4];
#pragma unroll
      for (int k = 0; k < 4; ++k) acc[k] = 0.f;
      for (int j = 0; j < TNO; ++j) {
        int base = (l + 199 - j) * 17 + sb;
        int kb = j * 16 + sb;
#pragma unroll
        for (int k = 0; k < 4; ++k)
          acc[k] = fmaf(ekl[kb + k], sE[base + k], fmaf(ikl[kb + k], sI[base + k], acc[k]));
      }
#pragma unroll
      for (int k = 0; k < 4; ++k) part[l * 17 + sb + k] = acc[k];
      __syncthreads();
      if (w == 0) {
        int t = t0 + l;
        float a[16];
#pragma unroll
        for (int s = 0; s < 16; ++s) a[s] = part[l * 17 + s];
        float th[16], ew[16]; int cm[16];
#pragma unroll
        for (int s = 0; s < 16; ++s) { th[s] = theta[s]; ew[s] = ewsub[s]; cm[s] = cmask[s]; }
        float val[16];
#pragma unroll
        for (int s = 0; s < 16; ++s) val[s] = 0.f;
#pragma unroll
        for (int sidx = 15; sidx >= 1; --sidx) {
          float sum = a[sidx] + th[sidx];
#pragma unroll
          for (int j = 0; j < 16; ++j)
            if ((cm[sidx] >> j) & 1) sum += val[j] * ew[j];
          val[sidx] = tanhf(sum);
        }
        float drive = a[0] + th[0];
#pragma unroll
        for (int j = 0; j < 16; ++j)
          if ((cm[0] >> j) & 1) drive += val[j] * ew[j];
        if (t < T_DATA) negd[t] = -drive;
        __threadfence();
        if (l == 0) { atomicExch(&filtFlag[b], 1); atomicAdd(filtCnt, 1); }
      }
      __syncthreads();
    }
    return;
  }

  // ---------------- scan role: wave0 = pure R14; wave1 polls ----------------
  {
    __shared__ float hpad[328];
    __shared__ unsigned long long mring[8];
    __shared__ float deepb[2][3][64];
    int wid = tid >> 6, l = tid & 63;
    for (int i = tid; i < 328; i += 256) hpad[i] = (i >= 64 && i < 264) ? hist[i - 64] : 0.f;
    if (tid < 8) mring[tid] = 0ull;
    for (int i = tid; i < 2 * 3 * 64; i += 256) (&deepb[0][0][0])[i] = 0.f;
    __syncthreads();

    // prologue gate: wave1 lane0 confirms filt blocks 0 and 1, fences.
    if (wid == 1 && l == 0) {
      while (atomicAdd(&filtFlag[0], 0) == 0) __builtin_amdgcn_s_sleep(8);
      while (atomicAdd(&filtFlag[1], 0) == 0) __builtin_amdgcn_s_sleep(8);
      __threadfence();
    }
    __syncthreads();

    float h0=0,h1=0,h2=0,h3=0,h4=0,h5=0,h6=0,h7=0,h8=0,h9=0,h10=0,h11=0,h12=0,h13=0,h14=0,h15=0,
          h16=0,h17=0,h18=0,h19=0,h20=0,h21=0,h22=0,h23=0,h24=0,h25=0,h26=0,h27=0,h28=0,h29=0,h30=0,h31=0,
          h32=0,h33=0,h34=0,h35=0,h36=0,h37=0,h38=0,h39=0,h40=0,h41=0,h42=0,h43=0,h44=0,h45=0,h46=0,h47=0,
          h48=0,h49=0,h50=0,h51=0,h52=0,h53=0,h54=0,h55=0,h56=0,h57=0,h58=0,h59=0,h60=0,h61=0,h62=0,h63=0,
          h64=0,h65=0,h66=0,h67=0,h68=0,h69=0,h70=0,h71=0,h72=0,h73=0,h74=0,h75=0,h76=0,h77=0,h78=0,h79=0,
          h80=0,h81=0,h82=0,h83=0,h84=0,h85=0,h86=0,h87=0,h88=0,h89=0,h90=0,h91=0,h92=0,h93=0,h94=0,h95=0,
          h96=0,h97=0,h98=0,h99=0,h100=0,h101=0,h102=0,h103=0,h104=0,h105=0,h106=0,h107=0,h108=0,h109=0,h110=0,h111=0,
          h112=0,h113=0,h114=0,h115=0,h116=0,h117=0,h118=0,h119=0,h120=0,h121=0,h122=0,h123=0,h124=0,h125=0,h126=0,h127=0;
    float ta0=0,ta1=0,ta2=0,ta3=0,ta4=0,ta5=0,ta6=0,ta7=0,
          ta8=0,ta9=0,ta10=0,ta11=0,ta12=0,ta13=0,ta14=0,ta15=0,
          ta16=0,ta17=0,ta18=0,ta19=0,ta20=0,ta21=0,ta22=0,ta23=0,
          ta24=0,ta25=0,ta26=0,ta27=0,ta28=0,ta29=0,ta30=0,ta31=0;
    float hd0=0,hd1=0,hd2=0,hd3=0,hd4=0,hd5=0,hd6=0,hd7=0,hd8=0,hd9=0,hd10=0,hd11=0,hd12=0,hd13=0,hd14=0,hd15=0,
          hd16=0,hd17=0,hd18=0,hd19=0,hd20=0,hd21=0,hd22=0,hd23=0,hd24=0,hd25=0,hd26=0,hd27=0,hd28=0,hd29=0,hd30=0,hd31=0,
          hd32=0,hd33=0,hd34=0,hd35=0,hd36=0,hd37=0,hd38=0,hd39=0,hd40=0,hd41=0,hd42=0,hd43=0,hd44=0,hd45=0;
    if (wid == 0) {
#define LD(j) h##j = hpad[l + j];
      LD(0)LD(1)LD(2)LD(3)LD(4)LD(5)LD(6)LD(7)LD(8)LD(9)LD(10)LD(11)LD(12)LD(13)LD(14)LD(15)
      LD(16)LD(17)LD(18)LD(19)LD(20)LD(21)LD(22)LD(23)LD(24)LD(25)LD(26)LD(27)LD(28)LD(29)LD(30)LD(31)
      LD(32)LD(33)LD(34)LD(35)LD(36)LD(37)LD(38)LD(39)LD(40)LD(41)LD(42)LD(43)LD(44)LD(45)LD(46)LD(47)
      LD(48)LD(49)LD(50)LD(51)LD(52)LD(53)LD(54)LD(55)LD(56)LD(57)LD(58)LD(59)LD(60)LD(61)LD(62)LD(63)
      LD(64)LD(65)LD(66)LD(67)LD(68)LD(69)LD(70)LD(71)LD(72)LD(73)LD(74)LD(75)LD(76)LD(77)LD(78)LD(79)
      LD(80)LD(81)LD(82)LD(83)LD(84)LD(85)LD(86)LD(87)LD(88)LD(89)LD(90)LD(91)LD(92)LD(93)LD(94)LD(95)
      LD(96)LD(97)LD(98)LD(99)LD(100)LD(101)LD(102)LD(103)LD(104)LD(105)LD(106)LD(107)LD(108)LD(109)LD(110)LD(111)
      LD(112)LD(113)LD(114)LD(115)LD(116)LD(117)LD(118)LD(119)LD(120)LD(121)LD(122)LD(123)LD(124)LD(125)LD(126)LD(127)
#undef LD
    } else {
      int dbase = (wid == 2) ? 174 : (wid == 3) ? 219 : 128;
#define LHD(j) hd##j = hpad[dbase + l + j];
      LHD(0)LHD(1)LHD(2)LHD(3)LHD(4)LHD(5)LHD(6)LHD(7)LHD(8)LHD(9)LHD(10)LHD(11)LHD(12)LHD(13)LHD(14)LHD(15)
      LHD(16)LHD(17)LHD(18)LHD(19)LHD(20)LHD(21)LHD(22)LHD(23)LHD(24)LHD(25)LHD(26)LHD(27)LHD(28)LHD(29)LHD(30)LHD(31)
      LHD(32)LHD(33)LHD(34)LHD(35)LHD(36)LHD(37)LHD(38)LHD(39)LHD(40)LHD(41)LHD(42)LHD(43)LHD(44)LHD(45)
#undef LHD
    }

    float bnd = 0.f;
    float ndv = 0.f;
    if (wid == 0) {
      ndv = negd[l];
      ta0 = ndv - h63;  ta1 = ndv - h61;  ta2 = ndv - h59;  ta3 = ndv - h57;
      ta4 = ndv - h55;  ta5 = ndv - h53;  ta6 = ndv - h51;  ta7 = ndv - h49;
      ta8 = ndv - h47;  ta9 = ndv - h45;  ta10 = ndv - h43; ta11 = ndv - h41;
      ta12 = ndv - h39; ta13 = ndv - h37; ta14 = ndv - h35; ta15 = ndv - h33;
      ta16 = ndv - h31; ta17 = ndv - h29; ta18 = ndv - h27; ta19 = ndv - h25;
      ta20 = ndv - h23; ta21 = ndv - h21; ta22 = ndv - h19; ta23 = ndv - h17;
      ta24 = ndv - h15; ta25 = ndv - h13; ta26 = ndv - h11; ta27 = ndv - h9;
      ta28 = ndv - h7;  ta29 = ndv - h5;  ta30 = ndv - h3;  ta31 = ndv - h1;
    }

    for (int n = 0; n < NBLK; ++n) {
      int t0 = n * 64;
      if (wid == 0) {
        // PURE R14 body — no atomics, no fences.
        int tn = t0 + 64 + l;
        float ndnext = (tn < T_DATA) ? negd[tn] : INFINITY;
        int par = n & 1;
        float X = deepb[par][0][l] + deepb[par][1][l] + deepb[par][2][l] + bnd;
        unsigned long long msk = 0ull;
        float bnd0 = 0.f, bnd1 = 0.f;
#define CH2(p, i, hvA, hvB, hbA, hbB) { \
        unsigned long long bm0, bm1; \
        asm("v_cmp_gt_f32 %0, %2, %3\n\t" \
            "v_cmp_gt_f32 %1, %2, %4" \
            : "=s"(bm0), "=s"(bm1) : "v"(X), "v"(ndv), "v"(ta##p)); \
        unsigned s0b = (unsigned)(bm0 >> (i)) & 1u; \
        unsigned long long bmx = s0b ? bm1 : bm0; \
        unsigned s1b = (unsigned)(bmx >> ((i) + 1)) & 1u; \
        float s0f = (float)s0b, s1f = (float)s1b; \
        X = fmaf(s0f, hvA, X); \
        X = fmaf(s1f, hvB, X); \
        bnd0 = fmaf(s0f, hbA, bnd0); \
        bnd1 = fmaf(s1f, hbB, bnd1); \
        ta##p = ndnext - hvA; \
        msk |= ((unsigned long long)s0b << (i)) | ((unsigned long long)s1b << ((i) + 1)); }
        CH2(0,0,h63,h62,h127,h126)   CH2(1,2,h61,h60,h125,h124)
        CH2(2,4,h59,h58,h123,h122)   CH2(3,6,h57,h56,h121,h120)
        CH2(4,8,h55,h54,h119,h118)   CH2(5,10,h53,h52,h117,h116)
        CH2(6,12,h51,h50,h115,h114)  CH2(7,14,h49,h48,h113,h112)
        CH2(8,16,h47,h46,h111,h110)  CH2(9,18,h45,h44,h109,h108)
        CH2(10,20,h43,h42,h107,h106) CH2(11,22,h41,h40,h105,h104)
        CH2(12,24,h39,h38,h103,h102) CH2(13,26,h37,h36,h101,h100)
        CH2(14,28,h35,h34,h99,h98)   CH2(15,30,h33,h32,h97,h96)
        CH2(16,32,h31,h30,h95,h94)   CH2(17,34,h29,h28,h93,h92)
        CH2(18,36,h27,h26,h91,h90)   CH2(19,38,h25,h24,h89,h88)
        CH2(20,40,h23,h22,h87,h86)   CH2(21,42,h21,h20,h85,h84)
        CH2(22,44,h19,h18,h83,h82)   CH2(23,46,h17,h16,h81,h80)
        CH2(24,48,h15,h14,h79,h78)   CH2(25,50,h13,h12,h77,h76)
        CH2(26,52,h11,h10,h75,h74)   CH2(27,54,h9,h8,h73,h72)
        CH2(28,56,h7,h6,h71,h70)     CH2(29,58,h5,h4,h69,h68)
        CH2(30,60,h3,h2,h67,h66)     CH2(31,62,h1,h0,h65,h64)
#undef CH2
        bnd = bnd0 + bnd1;
        float myspk = (float)((msk >> l) & 1ull);
        int t = t0 + l;
        if (t < T_DATA) out_spk[t] = myspk;
        if (l == 0) mring[n & 7] = msk;
        ndv = ndnext;
      } else {
        unsigned long long M1 = mring[(n + 7) & 7];
        unsigned long long M2 = mring[(n + 6) & 7];
        unsigned long long M3 = mring[(n + 5) & 7];
        M1 = ((unsigned long long)__builtin_amdgcn_readfirstlane((unsigned)(M1 >> 32)) << 32)
             | (unsigned)__builtin_amdgcn_readfirstlane((unsigned)M1);
        M2 = ((unsigned long long)__builtin_amdgcn_readfirstlane((unsigned)(M2 >> 32)) << 32)
             | (unsigned)__builtin_amdgcn_readfirstlane((unsigned)M2);
        M3 = ((unsigned long long)__builtin_amdgcn_readfirstlane((unsigned)(M3 >> 32)) << 32)
             | (unsigned)__builtin_amdgcn_readfirstlane((unsigned)M3);
        float a0 = 0.f, a1 = 0.f, a2 = 0.f, a3 = 0.f;
#define DT(j, M, b, acc) acc = fmaf((float)(((M) >> (b)) & 1ull), hd##j, acc);
        if (wid == 1) {
          DT(0,M1,63,a0)DT(1,M1,62,a1)DT(2,M1,61,a2)DT(3,M1,60,a3)
          DT(4,M1,59,a0)DT(5,M1,58,a1)DT(6,M1,57,a2)DT(7,M1,56,a3)
          DT(8,M1,55,a0)DT(9,M1,54,a1)DT(10,M1,53,a2)DT(11,M1,52,a3)
          DT(12,M1,51,a0)DT(13,M1,50,a1)DT(14,M1,49,a2)DT(15,M1,48,a3)
          DT(16,M1,47,a0)DT(17,M1,46,a1)DT(18,M1,45,a2)DT(19,M1,44,a3)
          DT(20,M1,43,a0)DT(21,M1,42,a1)DT(22,M1,41,a2)DT(23,M1,40,a3)
          DT(24,M1,39,a0)DT(25,M1,38,a1)DT(26,M1,37,a2)DT(27,M1,36,a3)
          DT(28,M1,35,a0)DT(29,M1,34,a1)DT(30,M1,33,a2)DT(31,M1,32,a3)
          DT(32,M1,31,a0)DT(33,M1,30,a1)DT(34,M1,29,a2)DT(35,M1,28,a3)
          DT(36,M1,27,a0)DT(37,M1,26,a1)DT(38,M1,25,a2)DT(39,M1,24,a3)
          DT(40,M1,23,a0)DT(41,M1,22,a1)DT(42,M1,21,a2)DT(43,M1,20,a3)
          DT(44,M1,19,a0)DT(45,M1,18,a1)
        } else if (wid == 2) {
          DT(0,M1,17,a0)DT(1,M1,16,a1)DT(2,M1,15,a2)DT(3,M1,14,a3)
          DT(4,M1,13,a0)DT(5,M1,12,a1)DT(6,M1,11,a2)DT(7,M1,10,a3)
          DT(8,M1,9,a0)DT(9,M1,8,a1)DT(10,M1,7,a2)DT(11,M1,6,a3)
          DT(12,M1,5,a0)DT(13,M1,4,a1)DT(14,M1,3,a2)DT(15,M1,2,a3)
          DT(16,M1,1,a0)DT(17,M1,0,a1)
          DT(18,M2,63,a2)DT(19,M2,62,a3)
          DT(20,M2,61,a0)DT(21,M2,60,a1)DT(22,M2,59,a2)DT(23,M2,58,a3)
          DT(24,M2,57,a0)DT(25,M2,56,a1)DT(26,M2,55,a2)DT(27,M2,54,a3)
          DT(28,M2,53,a0)DT(29,M2,52,a1)DT(30,M2,51,a2)DT(31,M2,50,a3)
          DT(32,M2,49,a0)DT(33,M2,48,a1)DT(34,M2,47,a2)DT(35,M2,46,a3)
          DT(36,M2,45,a0)DT(37,M2,44,a1)DT(38,M2,43,a2)DT(39,M2,42,a3)
          DT(40,M2,41,a0)DT(41,M2,40,a1)DT(42,M2,39,a2)DT(43,M2,38,a3)
          DT(44,M2,37,a0)
        } else {
          DT(0,M2,36,a0)DT(1,M2,35,a1)DT(2,M2,34,a2)DT(3,M2,33,a3)
          DT(4,M2,32,a0)DT(5,M2,31,a1)DT(6,M2,30,a2)DT(7,M2,29,a3)
          DT(8,M2,28,a0)DT(9,M2,27,a1)DT(10,M2,26,a2)DT(11,M2,25,a3)
          DT(12,M2,24,a0)DT(13,M2,23,a1)DT(14,M2,22,a2)DT(15,M2,21,a3)
          DT(16,M2,20,a0)DT(17,M2,19,a1)DT(18,M2,18,a2)DT(19,M2,17,a3)
          DT(20,M2,16,a0)DT(21,M2,15,a1)DT(22,M2,14,a2)DT(23,M2,13,a3)
          DT(24,M2,12,a0)DT(25,M2,11,a1)DT(26,M2,10,a2)DT(27,M2,9,a3)
          DT(28,M2,8,a0)DT(29,M2,7,a1)DT(30,M2,6,a2)DT(31,M2,5,a3)
          DT(32,M2,4,a0)DT(33,M2,3,a1)DT(34,M2,2,a2)DT(35,M2,1,a3)
          DT(36,M2,0,a0)
          DT(37,M3,63,a1)DT(38,M3,62,a2)DT(39,M3,61,a3)
          DT(40,M3,60,a0)DT(41,M3,59,a1)DT(42,M3,58,a2)DT(43,M3,57,a3)
          DT(44,M3,56,a0)
        }
#undef DT
        deepb[(n + 1) & 1][wid - 1][l] = (a0 + a1) + (a2 + a3);
        // wave1 lane0: confirm the flag wave0 needs NEXT iteration (n+1's
        // prefetch touches block n+2) — overlapped with wave0's chain.
        if (wid == 1 && l == 0) {
          int nb = n + 2; if (nb > NBLK - 1) nb = NBLK - 1;
          while (atomicAdd(&filtFlag[nb], 0) == 0) __builtin_amdgcn_s_sleep(8);
          __threadfence();
        }
      }
      __syncthreads();
    }
  }
}

// ---------------------------------------------------------------------------
extern "C" void kernel_launch(void* const* d_in, const int* in_sizes, int n_in,
                              void* d_out, int out_size, void* d_ws, size_t ws_size,
                              hipStream_t stream) {
  const float* S_e      = (const float*)d_in[0];
  const float* S_i      = (const float*)d_in[1];
  const int*   C_den    = (const int*)d_in[2];
  const float* C_syn_e  = (const float*)d_in[3];
  const float* C_syn_i  = (const float*)d_in[4];
  const float* cos_b    = (const float*)d_in[5];
  const float* Tau_e    = (const float*)d_in[6];
  const float* Tau_i    = (const float*)d_in[7];
  const float* W_e      = (const float*)d_in[8];
  const float* W_i      = (const float*)d_in[9];
  const float* D_e      = (const float*)d_in[10];
  const float* D_i      = (const float*)d_in[11];
  const float* W_sub    = (const float*)d_in[12];
  const float* W_hist   = (const float*)d_in[13];
  const float* Theta    = (const float*)d_in[14];
  float* out = (float*)d_out;

  float* wsf      = (float*)d_ws;
  float* ws_ek    = wsf;
  float* ws_ik    = wsf + 3200;
  float* ws_hist  = wsf + 6400;
  float* ws_ewsub = wsf + 6600;
  float* ws_we    = wsf + 6616;
  float* ws_wi    = wsf + 8616;
  float* synE     = wsf + 16384;
  float* synI     = wsf + 336384;
  float* negd     = wsf + 656384;
  int*   ws_me    = (int*)(wsf + 676384);
  int*   ws_mi    = (int*)(wsf + 678384);
  int*   ws_cmask = (int*)(wsf + 678884);
  int*   aggFlag  = (int*)(wsf + 680000);
  int*   filtFlag = aggFlag + 1280;
  int*   filtCnt  = filtFlag + 320;

  // zero the pipeline flags every call (deterministic; ws not re-poisoned)
  hipMemsetAsync(aggFlag, 0, (1280 + 320 + 16) * sizeof(int), stream);

  k_prep<<<dim3(1), dim3(256), 0, stream>>>(
      C_syn_e, C_syn_i, cos_b, Tau_e, Tau_i, W_e, W_i, D_e, D_i, W_sub, W_hist,
      C_den, ws_ek, ws_ik, ws_hist, ws_ewsub, ws_we, ws_wi, ws_me, ws_mi,
      ws_cmask, out + T_DATA);

  k_fused<<<dim3(256), dim3(256), 0, stream>>>(
      (const float4*)S_e, (const float4*)S_i,
      (const float4*)ws_we, (const float4*)ws_wi, synE, synI,
      ws_ek, ws_ik, Theta, ws_ewsub, ws_cmask, negd,
      ws_hist, out, aggFlag, filtFlag, filtCnt);
}